// Round 10
// baseline (126.375 us; speedup 1.0000x reference)
//
#include <hip/hip_runtime.h>
#include <math.h>

#define NV 3
#define NC 32
#define HS 256
#define WS 256
#define HT 128
#define WT 128
#define ND 48
#define NPIX (HT*WT)             // 16384
#define HSP 259                  // padded rows: y+1 for y in [-1, 257]
#define WSP 259
#define ROW4 (WSP*8)             // float4 per padded row = 2072
#define IMG4 (HSP*ROW4)          // float4 per padded view = 536648
#define FEAT_T_ELEMS (NV*IMG4*4) // floats
#define NB_INTERIOR (NV*HS*2)    // 1536 blocks: one per (v,y,half-row)
#define NBORDER_PIX (3*(3*WSP + 3*HS))   // 4635 border pixels
#define NBORDER_F4  (NBORDER_PIX*8)      // 37080 float4
#define NB_BORDER   145                   // ceil(37080/256)

// ---- 4-lane (aligned quad) cross-lane reductions via DPP (VALU pipe) ----
__device__ __forceinline__ float dpp_sum4(float x) {
    int v;
    v = __builtin_amdgcn_update_dpp(0, __float_as_int(x), 0xB1, 0xF, 0xF, true); // quad_perm xor1
    x += __int_as_float(v);
    v = __builtin_amdgcn_update_dpp(0, __float_as_int(x), 0x4E, 0xF, 0xF, true); // quad_perm xor2
    x += __int_as_float(v);
    return x;
}
__device__ __forceinline__ float dpp_max4(float x) {
    int v;
    v = __builtin_amdgcn_update_dpp(0, __float_as_int(x), 0xB1, 0xF, 0xF, true);
    x = fmaxf(x, __int_as_float(v));
    v = __builtin_amdgcn_update_dpp(0, __float_as_int(x), 0x4E, 0xF, 0xF, true);
    x = fmaxf(x, __int_as_float(v));
    return x;
}

// component-wise float4 helpers (eligible for v_pk_fma_f32 packing)
__device__ __forceinline__ float4 f4mul(float4 a, float s) {
    return make_float4(a.x*s, a.y*s, a.z*s, a.w*s);
}
__device__ __forceinline__ float4 f4fma(float4 a, float s, float4 c) {
    return make_float4(fmaf(a.x,s,c.x), fmaf(a.y,s,c.y),
                       fmaf(a.z,s,c.z), fmaf(a.w,s,c.w));
}
__device__ __forceinline__ float4 f4fma2(float4 a, float4 c) {   // c += a*a
    return make_float4(fmaf(a.x,a.x,c.x), fmaf(a.y,a.y,c.y),
                       fmaf(a.z,a.z,c.z), fmaf(a.w,a.w,c.w));
}
__device__ __forceinline__ float4 f4add(float4 a, float4 b) {
    return make_float4(a.x+b.x, a.y+b.y, a.z+b.z, a.w+b.w);
}

// -------------------------------------------------------------------------
// Kernel A: (V,C,Hs,Ws) -> zero-padded (V,Hs+3,Ws+3,C) transpose + border
// zeroing + projection setup. Interior block = half a (v,y) row (1536
// blocks, 6/CU for latency hiding). Thread (q=tid&7, xl=tid>>3) does a
// register 4x4 transpose of 4 plane-float4s: per wave-instr loads = 8 full
// 128B segments, stores = 8 full 128B segments. 128 B moved per thread.
// -------------------------------------------------------------------------
__global__ __launch_bounds__(256) void prep(
        const float* __restrict__ src, float* __restrict__ dstf,
        const float* __restrict__ src_exts,
        const float* __restrict__ src_ints,
        const float* __restrict__ tar_exts,
        const float* __restrict__ tar_ints,
        float* __restrict__ proj_out) {
    float4* dst = (float4*)dstf;
    int bid = blockIdx.x;
    if (bid < NB_INTERIOR) {
        int v    = bid >> 9;                 // /512
        int rem  = bid & 511;
        int y    = rem >> 1;
        int half = rem & 1;
        int q    = threadIdx.x & 7;          // channel quad 0..7
        int xl   = threadIdx.x >> 3;         // 0..31
        int x0   = half*128 + xl*4;
        const float* in = src + ((size_t)(v*NC + q*4))*HS*WS + (size_t)y*WS;
        float4* drow = dst + (size_t)(v*HSP + y+1)*ROW4 + 8 + q;
        float4 p0 = *(const float4*)(in + x0);
        float4 p1 = *(const float4*)(in + HS*WS   + x0);
        float4 p2 = *(const float4*)(in + 2*HS*WS + x0);
        float4 p3 = *(const float4*)(in + 3*HS*WS + x0);
        drow[(x0+0)*8] = make_float4(p0.x, p1.x, p2.x, p3.x);
        drow[(x0+1)*8] = make_float4(p0.y, p1.y, p2.y, p3.y);
        drow[(x0+2)*8] = make_float4(p0.z, p1.z, p2.z, p3.z);
        drow[(x0+3)*8] = make_float4(p0.w, p1.w, p2.w, p3.w);
        return;
    }
    // border zeroing
    int t = (bid - NB_INTERIOR)*256 + threadIdx.x;
    if (t < NBORDER_F4) {
        int pixb = t >> 3, q = t & 7;
        int v = pixb / (NBORDER_PIX/3);
        int r = pixb - v*(NBORDER_PIX/3);
        int y, x;
        if (r < 3*WSP) {                      // rows y=0,257,258 full width
            int band = r / WSP;
            y = (band == 0) ? 0 : (band == 1 ? 257 : 258);
            x = r - band*WSP;
        } else {                              // cols x=0,257,258, y=1..256
            int rr = r - 3*WSP;
            int band = rr >> 8;
            x = (band == 0) ? 0 : (band == 1 ? 257 : 258);
            y = 1 + (rr & 255);
        }
        dst[(v*HSP + y)*WSP*8 + x*8 + q] = make_float4(0.f,0.f,0.f,0.f);
    }
    // projection matrices: one thread, alongside border work
    if (bid == NB_INTERIOR && threadIdx.x == 0) {
        float Kt[9], Et[16];
        for (int i = 0; i < 9;  i++) Kt[i] = tar_ints[i];
        for (int i = 0; i < 16; i++) Et[i] = tar_exts[i];
        float T[12];
        for (int rI = 0; rI < 3; rI++)
            for (int col = 0; col < 4; col++) {
                float s = 0.f;
                for (int k = 0; k < 3; k++) s += Kt[rI*3+k] * Et[k*4+col];
                T[rI*4+col] = s;
            }
        float M[9]  = {T[0],T[1],T[2], T[4],T[5],T[6], T[8],T[9],T[10]};
        float tv[3] = {T[3],T[7],T[11]};
        float det = M[0]*(M[4]*M[8]-M[5]*M[7])
                  - M[1]*(M[3]*M[8]-M[5]*M[6])
                  + M[2]*(M[3]*M[7]-M[4]*M[6]);
        float id = 1.0f/det;
        float Mi[9];
        Mi[0] =  (M[4]*M[8]-M[5]*M[7])*id;
        Mi[1] = -(M[1]*M[8]-M[2]*M[7])*id;
        Mi[2] =  (M[1]*M[5]-M[2]*M[4])*id;
        Mi[3] = -(M[3]*M[8]-M[5]*M[6])*id;
        Mi[4] =  (M[0]*M[8]-M[2]*M[6])*id;
        Mi[5] = -(M[0]*M[5]-M[2]*M[3])*id;
        Mi[6] =  (M[3]*M[7]-M[4]*M[6])*id;
        Mi[7] = -(M[0]*M[7]-M[1]*M[6])*id;
        Mi[8] =  (M[0]*M[4]-M[1]*M[3])*id;
        float mt[3];
        for (int rI = 0; rI < 3; rI++)
            mt[rI] = -(Mi[rI*3+0]*tv[0] + Mi[rI*3+1]*tv[1] + Mi[rI*3+2]*tv[2]);
        float inv4[16] = {Mi[0],Mi[1],Mi[2],mt[0],
                          Mi[3],Mi[4],Mi[5],mt[1],
                          Mi[6],Mi[7],Mi[8],mt[2],
                          0.f,0.f,0.f,1.f};
        for (int v = 0; v < NV; v++) {
            const float* Ks = src_ints + v*9;
            const float* Ev = src_exts + v*16;
            float P34[12];
            for (int rI = 0; rI < 3; rI++)
                for (int col = 0; col < 4; col++) {
                    float s = 0.f;
                    for (int k = 0; k < 3; k++) s += Ks[rI*3+k] * Ev[k*4+col];
                    P34[rI*4+col] = s;
                }
            for (int rI = 0; rI < 3; rI++)
                for (int col = 0; col < 4; col++) {
                    float s = 0.f;
                    for (int k = 0; k < 4; k++) s += P34[rI*4+k] * inv4[k*4+col];
                    proj_out[v*12 + rI*4 + col] = s;
                }
        }
    }
}

// -------------------------------------------------------------------------
// Kernel B: fused plane-sweep + variance cost + softmax + depth/CI.
// Block = 512 threads (8 waves) x 16 pixels; DEPTH-LOCKSTEP: at step dd all
// 8 waves process adjacent depths {dd*8..dd*8+7} (wave w -> depth dd*8+w),
// with __syncthreads() per step. Concurrent source footprint ~8 adjacent
// depth-slices (~15-20KB) -> L1-resident -> tap reuse hits L1 not L2
// (r6-r9 were L2-BW-bound at ~28 TB/s on 1.21 GB of tap reads).
// Lane = p*4+q; two-phase body (r8): phase 1 projection/offsets/weights
// per view once (serves 16 px/wave), phase 2 channel-halves x views.
// -------------------------------------------------------------------------
__global__ __launch_bounds__(512, 4) void depth_main(
        const float4* __restrict__ featT,
        const float* __restrict__ proj,
        const float* __restrict__ near_far,
        float* __restrict__ out) {
    __shared__ float cl[16][49];   // stride 49 (odd): writer lanes spread banks

    const int tid  = threadIdx.x;
    const int w    = tid >> 6;       // wave index (0..7)
    const int lane = tid & 63;
    const int p    = lane >> 2;      // pixel within block (0..15)
    const int q    = lane & 3;       // channel quad owner

    // XCD swizzle: 1024 blocks, XCD k owns logical [k*128, k*128+128)
    const int lb  = ((blockIdx.x & 7) << 7) | (blockIdx.x >> 3);
    const int pix = lb*16 + p;
    const float cx = (pix & (WT-1)) + 0.5f;
    const float cy = (pix >> 7) + 0.5f;

    const float nearv = near_far[pix];
    const float farv  = near_far[NPIX + pix];
    const float step  = (farv - nearv) * (1.0f/(ND-1));

    for (int dd = 0; dd < 6; dd++) {
        const int   d  = dd*8 + w;             // lockstep: waves on adjacent depths
        const float dv = fmaf(step, (float)d, nearv);
        unsigned o0[NV];
        float w00[NV], w01[NV], w10[NV], w11[NV];
        // ---- phase 1: projection + addressing per view (shared by halves)
        #pragma unroll
        for (int v = 0; v < NV; v++) {
            const float* P = proj + v*12;   // uniform -> SGPRs
            float rxv = fmaf(P[0], cx, fmaf(P[1], cy, P[2]));
            float ryv = fmaf(P[4], cx, fmaf(P[5], cy, P[6]));
            float rzv = fmaf(P[8], cx, fmaf(P[9], cy, P[10]));
            float pxx = fmaf(rxv, dv, P[3]);
            float pyy = fmaf(ryv, dv, P[7]);
            float pzz = fmaf(rzv, dv, P[11]);
            float invz = __builtin_amdgcn_rcpf(fmaxf(pzz, 1e-6f));
            // padded coords: sp = s_unpadded + 1, range [0, 257]
            float sxp = fminf(fmaxf(fmaf(pxx, invz, 0.5f), 0.0f), 257.0f);
            float syp = fminf(fmaxf(fmaf(pyy, invz, 0.5f), 0.0f), 257.0f);
            float x0f = floorf(sxp), y0f = floorf(syp);
            float wx = sxp - x0f,   wy = syp - y0f;
            unsigned xi = (unsigned)(int)x0f;     // 0..257
            unsigned yi = (unsigned)(int)y0f;     // 0..257
            o0[v] = (unsigned)(v*IMG4) + yi*ROW4 + xi*8u + (unsigned)q;
            float a11 = wx*wy;
            w11[v] = a11;
            w10[v] = wy - a11;
            w01[v] = wx - a11;
            w00[v] = (1.0f - wx) - (wy - a11);
        }
        // ---- phase 2: two channel-halves x views, shared tap registers
        float m2_tot = 0.f;
        float4 a4 = make_float4(0.f,0.f,0.f,0.f);
        #pragma unroll
        for (int h = 0; h < 2; h++) {
            float4 m4 = make_float4(0.f,0.f,0.f,0.f);
            #pragma unroll
            for (int v = 0; v < NV; v++) {
                float4 f00 = featT[o0[v] + 4*h];
                float4 f01 = featT[o0[v] + 4*h + 8];
                float4 f10 = featT[o0[v] + 4*h + ROW4];
                float4 f11 = featT[o0[v] + 4*h + ROW4 + 8];
                float4 val = f4fma(f11, w11[v], f4fma(f10, w10[v],
                             f4fma(f01, w01[v], f4mul(f00, w00[v]))));
                a4 = f4fma2(val, a4);
                m4 = f4add(m4, val);
            }
            m2_tot += (m4.x*m4.x + m4.y*m4.y) + (m4.z*m4.z + m4.w*m4.w);
        }
        float a_tot = (a4.x + a4.y) + (a4.z + a4.w);
        a_tot  = dpp_sum4(a_tot);
        m2_tot = dpp_sum4(m2_tot);
        float cost = (a_tot*(1.0f/3.0f) - m2_tot*(1.0f/9.0f)) * (1.0f/32.0f);
        if (q == 0) cl[p][d] = cost;
        __syncthreads();   // keep waves depth-synchronized (L1 locality)
    }

    if (w != 0) return;

    // softmax over 48 depths: lane q holds depths q*12..q*12+11
    float n[12], e[12];
    #pragma unroll
    for (int j = 0; j < 12; j++) n[j] = -cl[p][q*12 + j];
    float mx = n[0];
    #pragma unroll
    for (int j = 1; j < 12; j++) mx = fmaxf(mx, n[j]);
    mx = dpp_max4(mx);
    float s0 = 0.f, s1 = 0.f;
    #pragma unroll
    for (int j = 0; j < 12; j++) {
        float dvj = fmaf(step, (float)(q*12 + j), nearv);
        e[j] = __expf(n[j] - mx);
        s0 += e[j];
        s1 = fmaf(e[j], dvj, s1);
    }
    s0 = dpp_sum4(s0);
    s1 = dpp_sum4(s1);
    float depth = s1 / s0;
    float s2 = 0.f;
    #pragma unroll
    for (int j = 0; j < 12; j++) {
        float qd = fmaf(step, (float)(q*12 + j), nearv) - depth;
        s2 = fmaf(e[j]*qd, qd, s2);
    }
    s2 = dpp_sum4(s2);
    float var = s2 / s0;
    float hci = sqrtf(fmaxf(var, 1e-12f));
    if (q == 0) {
        out[pix]          = depth;
        out[NPIX + pix]   = fmaxf(depth - hci, nearv);
        out[2*NPIX + pix] = fminf(depth + hci, farv);
    }
}

// -------------------------------------------------------------------------
extern "C" void kernel_launch(void* const* d_in, const int* in_sizes, int n_in,
                              void* d_out, int out_size, void* d_ws, size_t ws_size,
                              hipStream_t stream) {
    const float* src_feat = (const float*)d_in[0];
    const float* src_exts = (const float*)d_in[1];
    const float* src_ints = (const float*)d_in[2];
    const float* tar_exts = (const float*)d_in[3];
    const float* tar_ints = (const float*)d_in[4];
    const float* near_far = (const float*)d_in[5];
    float* out   = (float*)d_out;
    float* featT = (float*)d_ws;                 // 25.8 MB padded transposed
    float* proj  = featT + FEAT_T_ELEMS;         // 36 floats

    hipLaunchKernelGGL(prep, dim3(NB_INTERIOR + NB_BORDER), dim3(256), 0, stream,
                       src_feat, featT, src_exts, src_ints, tar_exts, tar_ints, proj);
    hipLaunchKernelGGL(depth_main, dim3(NPIX/16), dim3(512), 0, stream,
                       (const float4*)featT, proj, near_far, out);
}

// Round 11
// 121.633 us; speedup vs baseline: 1.0390x; 1.0390x over previous
//
#include <hip/hip_runtime.h>
#include <math.h>

#define NV 3
#define NC 32
#define HS 256
#define WS 256
#define HT 128
#define WT 128
#define ND 48
#define NPIX (HT*WT)             // 16384
#define HSP 259                  // padded rows: y+1 for y in [-1, 257]
#define WSP 259
#define ROW4 (WSP*8)             // float4 per padded row = 2072
#define IMG4 (HSP*ROW4)          // float4 per padded view = 536648
#define FEAT_T_ELEMS (NV*IMG4*4) // floats
#define NB_INTERIOR (NV*HS*2)    // 1536 blocks: one per (v,y,half-row)
#define NBORDER_PIX (3*(3*WSP + 3*HS))   // 4635 border pixels
#define NBORDER_F4  (NBORDER_PIX*8)      // 37080 float4
#define NB_BORDER   145                   // ceil(37080/256)

// ---- 8-lane (aligned group) cross-lane reductions via DPP (VALU pipe) ----
__device__ __forceinline__ float dpp_sum8(float x) {
    int v;
    v = __builtin_amdgcn_update_dpp(0, __float_as_int(x), 0xB1,  0xF, 0xF, true); // quad_perm xor1
    x += __int_as_float(v);
    v = __builtin_amdgcn_update_dpp(0, __float_as_int(x), 0x4E,  0xF, 0xF, true); // quad_perm xor2
    x += __int_as_float(v);
    v = __builtin_amdgcn_update_dpp(0, __float_as_int(x), 0x141, 0xF, 0xF, true); // row_half_mirror
    x += __int_as_float(v);
    return x;
}
__device__ __forceinline__ float dpp_max8(float x) {
    int v;
    v = __builtin_amdgcn_update_dpp(0, __float_as_int(x), 0xB1,  0xF, 0xF, true);
    x = fmaxf(x, __int_as_float(v));
    v = __builtin_amdgcn_update_dpp(0, __float_as_int(x), 0x4E,  0xF, 0xF, true);
    x = fmaxf(x, __int_as_float(v));
    v = __builtin_amdgcn_update_dpp(0, __float_as_int(x), 0x141, 0xF, 0xF, true);
    x = fmaxf(x, __int_as_float(v));
    return x;
}

// component-wise float4 helpers (eligible for v_pk_fma_f32 packing)
__device__ __forceinline__ float4 f4mul(float4 a, float s) {
    return make_float4(a.x*s, a.y*s, a.z*s, a.w*s);
}
__device__ __forceinline__ float4 f4fma(float4 a, float s, float4 c) {
    return make_float4(fmaf(a.x,s,c.x), fmaf(a.y,s,c.y),
                       fmaf(a.z,s,c.z), fmaf(a.w,s,c.w));
}
__device__ __forceinline__ float4 f4fma2(float4 a, float4 c) {   // c += a*a
    return make_float4(fmaf(a.x,a.x,c.x), fmaf(a.y,a.y,c.y),
                       fmaf(a.z,a.z,c.z), fmaf(a.w,a.w,c.w));
}
__device__ __forceinline__ float4 f4add(float4 a, float4 b) {
    return make_float4(a.x+b.x, a.y+b.y, a.z+b.z, a.w+b.w);
}

// -------------------------------------------------------------------------
// Kernel A: (V,C,Hs,Ws) -> zero-padded (V,Hs+3,Ws+3,C) transpose + border
// zeroing + projection setup. Interior block = half a (v,y) row; thread
// (q,xl) does a register 4x4 transpose. Per wave-instr: loads/stores are
// full 128-B segments.
// -------------------------------------------------------------------------
__global__ __launch_bounds__(256) void prep(
        const float* __restrict__ src, float* __restrict__ dstf,
        const float* __restrict__ src_exts,
        const float* __restrict__ src_ints,
        const float* __restrict__ tar_exts,
        const float* __restrict__ tar_ints,
        float* __restrict__ proj_out) {
    float4* dst = (float4*)dstf;
    int bid = blockIdx.x;
    if (bid < NB_INTERIOR) {
        int v    = bid >> 9;                 // /512
        int rem  = bid & 511;
        int y    = rem >> 1;
        int half = rem & 1;
        int q    = threadIdx.x & 7;          // channel quad 0..7
        int xl   = threadIdx.x >> 3;         // 0..31
        int x0   = half*128 + xl*4;
        const float* in = src + ((size_t)(v*NC + q*4))*HS*WS + (size_t)y*WS;
        float4* drow = dst + (size_t)(v*HSP + y+1)*ROW4 + 8 + q;
        float4 p0 = *(const float4*)(in + x0);
        float4 p1 = *(const float4*)(in + HS*WS   + x0);
        float4 p2 = *(const float4*)(in + 2*HS*WS + x0);
        float4 p3 = *(const float4*)(in + 3*HS*WS + x0);
        drow[(x0+0)*8] = make_float4(p0.x, p1.x, p2.x, p3.x);
        drow[(x0+1)*8] = make_float4(p0.y, p1.y, p2.y, p3.y);
        drow[(x0+2)*8] = make_float4(p0.z, p1.z, p2.z, p3.z);
        drow[(x0+3)*8] = make_float4(p0.w, p1.w, p2.w, p3.w);
        return;
    }
    // border zeroing
    int t = (bid - NB_INTERIOR)*256 + threadIdx.x;
    if (t < NBORDER_F4) {
        int pixb = t >> 3, q = t & 7;
        int v = pixb / (NBORDER_PIX/3);
        int r = pixb - v*(NBORDER_PIX/3);
        int y, x;
        if (r < 3*WSP) {                      // rows y=0,257,258 full width
            int band = r / WSP;
            y = (band == 0) ? 0 : (band == 1 ? 257 : 258);
            x = r - band*WSP;
        } else {                              // cols x=0,257,258, y=1..256
            int rr = r - 3*WSP;
            int band = rr >> 8;
            x = (band == 0) ? 0 : (band == 1 ? 257 : 258);
            y = 1 + (rr & 255);
        }
        dst[(v*HSP + y)*WSP*8 + x*8 + q] = make_float4(0.f,0.f,0.f,0.f);
    }
    // projection matrices: one thread, alongside border work
    if (bid == NB_INTERIOR && threadIdx.x == 0) {
        float Kt[9], Et[16];
        for (int i = 0; i < 9;  i++) Kt[i] = tar_ints[i];
        for (int i = 0; i < 16; i++) Et[i] = tar_exts[i];
        float T[12];
        for (int rI = 0; rI < 3; rI++)
            for (int col = 0; col < 4; col++) {
                float s = 0.f;
                for (int k = 0; k < 3; k++) s += Kt[rI*3+k] * Et[k*4+col];
                T[rI*4+col] = s;
            }
        float M[9]  = {T[0],T[1],T[2], T[4],T[5],T[6], T[8],T[9],T[10]};
        float tv[3] = {T[3],T[7],T[11]};
        float det = M[0]*(M[4]*M[8]-M[5]*M[7])
                  - M[1]*(M[3]*M[8]-M[5]*M[6])
                  + M[2]*(M[3]*M[7]-M[4]*M[6]);
        float id = 1.0f/det;
        float Mi[9];
        Mi[0] =  (M[4]*M[8]-M[5]*M[7])*id;
        Mi[1] = -(M[1]*M[8]-M[2]*M[7])*id;
        Mi[2] =  (M[1]*M[5]-M[2]*M[4])*id;
        Mi[3] = -(M[3]*M[8]-M[5]*M[6])*id;
        Mi[4] =  (M[0]*M[8]-M[2]*M[6])*id;
        Mi[5] = -(M[0]*M[5]-M[2]*M[3])*id;
        Mi[6] =  (M[3]*M[7]-M[4]*M[6])*id;
        Mi[7] = -(M[0]*M[7]-M[1]*M[6])*id;
        Mi[8] =  (M[0]*M[4]-M[1]*M[3])*id;
        float mt[3];
        for (int rI = 0; rI < 3; rI++)
            mt[rI] = -(Mi[rI*3+0]*tv[0] + Mi[rI*3+1]*tv[1] + Mi[rI*3+2]*tv[2]);
        float inv4[16] = {Mi[0],Mi[1],Mi[2],mt[0],
                          Mi[3],Mi[4],Mi[5],mt[1],
                          Mi[6],Mi[7],Mi[8],mt[2],
                          0.f,0.f,0.f,1.f};
        for (int v = 0; v < NV; v++) {
            const float* Ks = src_ints + v*9;
            const float* Ev = src_exts + v*16;
            float P34[12];
            for (int rI = 0; rI < 3; rI++)
                for (int col = 0; col < 4; col++) {
                    float s = 0.f;
                    for (int k = 0; k < 3; k++) s += Ks[rI*3+k] * Ev[k*4+col];
                    P34[rI*4+col] = s;
                }
            for (int rI = 0; rI < 3; rI++)
                for (int col = 0; col < 4; col++) {
                    float s = 0.f;
                    for (int k = 0; k < 4; k++) s += P34[rI*4+k] * inv4[k*4+col];
                    proj_out[v*12 + rI*4 + col] = s;
                }
        }
    }
}

// -------------------------------------------------------------------------
// Kernel B: fused plane-sweep + variance cost + softmax + depth/CI.
// Lane = p*8+q: 8 pixels x 8 channel-quads -> each tap is ONE full 128-B
// line per pixel per instruction (transaction-optimal; the 16px*4q layout
// costs 2x line-lookups, which was the r8-r10 ~31 us VMEM floor).
// Block = 512 threads (8 waves), DEPTH-LOCKSTEP: wave w does depth dd*8+w,
// __syncthreads per step (adjacent-depth taps stay L1/L2-hot).
// Grid 2048 -> 4 blocks/CU = 32 waves/CU (vs r6's 12) to hide tap latency.
// Per-view ray constants hoisted out of the depth loop (r6 body, ~40 VGPR).
// -------------------------------------------------------------------------
__global__ __launch_bounds__(512, 4) void depth_main(
        const float4* __restrict__ featT,
        const float* __restrict__ proj,
        const float* __restrict__ near_far,
        float* __restrict__ out) {
    __shared__ float cl[8][49];

    const int tid  = threadIdx.x;
    const int w    = tid >> 6;       // wave index (0..7) -> depth phase
    const int lane = tid & 63;
    const int p    = lane >> 3;      // pixel within block (0..7)
    const int q    = lane & 7;       // channel quad

    // XCD swizzle: 2048 blocks, XCD k owns logical [k*256, k*256+256)
    const int lb  = ((blockIdx.x & 7) << 8) | (blockIdx.x >> 3);
    const int pix = lb*8 + p;
    const float cx = (pix & (WT-1)) + 0.5f;
    const float cy = (pix >> 7) + 0.5f;

    float rx[NV], ry[NV], rz[NV], tx[NV], ty[NV], tz[NV];
    #pragma unroll
    for (int v = 0; v < NV; v++) {
        const float* P = proj + v*12;
        rx[v] = fmaf(P[0], cx, fmaf(P[1], cy, P[2]));  tx[v] = P[3];
        ry[v] = fmaf(P[4], cx, fmaf(P[5], cy, P[6]));  ty[v] = P[7];
        rz[v] = fmaf(P[8], cx, fmaf(P[9], cy, P[10])); tz[v] = P[11];
    }

    const float nearv = near_far[pix];
    const float farv  = near_far[NPIX + pix];
    const float step  = (farv - nearv) * (1.0f/(ND-1));

    for (int dd = 0; dd < 6; dd++) {
        const int   d  = dd*8 + w;       // lockstep: waves on adjacent depths
        const float dv = fmaf(step, (float)d, nearv);
        float4 a4 = make_float4(0.f,0.f,0.f,0.f);
        float4 m4 = make_float4(0.f,0.f,0.f,0.f);
        #pragma unroll
        for (int v = 0; v < NV; v++) {
            float pxx = fmaf(rx[v], dv, tx[v]);
            float pyy = fmaf(ry[v], dv, ty[v]);
            float pzz = fmaf(rz[v], dv, tz[v]);
            float invz = __builtin_amdgcn_rcpf(fmaxf(pzz, 1e-6f));
            // padded coords: sp = s_unpadded + 1, range [0, 257]
            float sxp = fminf(fmaxf(fmaf(pxx, invz, 0.5f), 0.0f), 257.0f);
            float syp = fminf(fmaxf(fmaf(pyy, invz, 0.5f), 0.0f), 257.0f);
            float x0f = floorf(sxp), y0f = floorf(syp);
            float wx = sxp - x0f,   wy = syp - y0f;
            unsigned xi = (unsigned)(int)x0f;     // 0..257
            unsigned yi = (unsigned)(int)y0f;     // 0..257
            unsigned idx = (unsigned)(v*IMG4) + yi*ROW4 + xi*8u + (unsigned)q;
            float4 f00 = featT[idx];
            float4 f01 = featT[idx + 8];
            float4 f10 = featT[idx + ROW4];
            float4 f11 = featT[idx + ROW4 + 8];
            float w11 = wx*wy;
            float w10 = wy - w11;
            float w01 = wx - w11;
            float w00 = (1.0f - wx) - w10;
            float4 val = f4fma(f11, w11, f4fma(f10, w10,
                         f4fma(f01, w01, f4mul(f00, w00))));
            a4 = f4fma2(val, a4);
            m4 = f4add(m4, val);
        }
        float a  = (a4.x + a4.y) + (a4.z + a4.w);
        float m2 = (m4.x*m4.x + m4.y*m4.y) + (m4.z*m4.z + m4.w*m4.w);
        a  = dpp_sum8(a);
        m2 = dpp_sum8(m2);
        float cost = (a*(1.0f/3.0f) - m2*(1.0f/9.0f)) * (1.0f/32.0f);
        if (q == 0) cl[p][d] = cost;
        __syncthreads();   // depth-lockstep (cache locality) + cl visibility
    }

    if (w != 0) return;

    // softmax over 48 depths: lane q holds depths q*6..q*6+5
    float n[6], e[6];
    #pragma unroll
    for (int j = 0; j < 6; j++) n[j] = -cl[p][q*6 + j];
    float mx = n[0];
    #pragma unroll
    for (int j = 1; j < 6; j++) mx = fmaxf(mx, n[j]);
    mx = dpp_max8(mx);
    float s0 = 0.f, s1 = 0.f;
    #pragma unroll
    for (int j = 0; j < 6; j++) {
        float dvj = fmaf(step, (float)(q*6 + j), nearv);
        e[j] = __expf(n[j] - mx);
        s0 += e[j];
        s1 = fmaf(e[j], dvj, s1);
    }
    s0 = dpp_sum8(s0);
    s1 = dpp_sum8(s1);
    float depth = s1 / s0;
    float s2 = 0.f;
    #pragma unroll
    for (int j = 0; j < 6; j++) {
        float qd = fmaf(step, (float)(q*6 + j), nearv) - depth;
        s2 = fmaf(e[j]*qd, qd, s2);
    }
    s2 = dpp_sum8(s2);
    float var = s2 / s0;
    float hci = sqrtf(fmaxf(var, 1e-12f));
    if (q == 0) {
        out[pix]          = depth;
        out[NPIX + pix]   = fmaxf(depth - hci, nearv);
        out[2*NPIX + pix] = fminf(depth + hci, farv);
    }
}

// -------------------------------------------------------------------------
extern "C" void kernel_launch(void* const* d_in, const int* in_sizes, int n_in,
                              void* d_out, int out_size, void* d_ws, size_t ws_size,
                              hipStream_t stream) {
    const float* src_feat = (const float*)d_in[0];
    const float* src_exts = (const float*)d_in[1];
    const float* src_ints = (const float*)d_in[2];
    const float* tar_exts = (const float*)d_in[3];
    const float* tar_ints = (const float*)d_in[4];
    const float* near_far = (const float*)d_in[5];
    float* out   = (float*)d_out;
    float* featT = (float*)d_ws;                 // 25.8 MB padded transposed
    float* proj  = featT + FEAT_T_ELEMS;         // 36 floats

    hipLaunchKernelGGL(prep, dim3(NB_INTERIOR + NB_BORDER), dim3(256), 0, stream,
                       src_feat, featT, src_exts, src_ints, tar_exts, tar_ints, proj);
    hipLaunchKernelGGL(depth_main, dim3(NPIX/8), dim3(512), 0, stream,
                       (const float4*)featT, proj, near_far, out);
}